// Round 1
// baseline (186.886 us; speedup 1.0000x reference)
//
#include <hip/hip_runtime.h>
#include <hip/hip_bf16.h>
#include <math.h>

#define B_ 4
#define N_ 8192
#define C_ 128
#define CN_ 64
#define M_ 32

// ---------- tiny: wq1[c] = Wq[c,:]·w_sa1, wk1[c] = Wk[c,:]·w_sa1 ----------
__global__ __launch_bounds__(256) void kW(const float* __restrict__ Wq,
                                          const float* __restrict__ Wk,
                                          const float* __restrict__ w1,
                                          float* __restrict__ wq1,
                                          float* __restrict__ wk1) {
    int t = threadIdx.x;
    if (t < C_) {
        float s = 0.f;
        for (int c2 = 0; c2 < CN_; ++c2) s += Wq[t * CN_ + c2] * w1[c2];
        wq1[t] = s;
    } else {
        int c = t - C_;
        float s = 0.f;
        for (int c2 = 0; c2 < CN_; ++c2) s += Wk[c * CN_ + c2] * w1[c2];
        wk1[c] = s;
    }
}

// ---------- vsum[b,c] = sum_n v[b,n,c]  (atomics into zeroed buffer) ----------
__global__ __launch_bounds__(256) void kVsum(const float* __restrict__ v,
                                             float* __restrict__ vsum) {
    int g = blockIdx.x;            // 256 blocks, 64 per b
    int b = g >> 6;
    int chunk = (g & 63) * 128;    // 128 rows per block
    int t = threadIdx.x;
    int c = t & 127, h = t >> 7;
    const float* vb = v + ((size_t)b * N_ + chunk) * C_;
    float acc = 0.f;
    for (int r = h; r < 128; r += 2) acc += vb[(size_t)r * C_ + c];
    __shared__ float red[256];
    red[t] = acc;
    __syncthreads();
    if (t < 128) atomicAdd(&vsum[b * C_ + t], red[t] + red[t + 128]);
}

// ---------- S_init[b,m,:] = (vsum - excluded_edge_rows) @ Wv ----------
__global__ __launch_bounds__(128) void kSinit(const float* __restrict__ v,
                                              const float* __restrict__ Wv,
                                              const float* __restrict__ vsum,
                                              float* __restrict__ S) {
    int g = blockIdx.x;   // 128 blocks = (b,m)
    int b = g >> 5, m = g & 31;
    int t = threadIdx.x;  // 128 threads
    __shared__ float vd[C_];
    float excl = 0.f;
    if (m > 16) {
        int kk = m - 16;                       // exclude first (m-16) rows
        for (int r = 0; r < kk; ++r) excl += v[((size_t)b * N_ + r) * C_ + t];
    } else if (m < 16) {
        int kk = 16 - m;                       // exclude last (16-m) rows
        for (int r = N_ - kk; r < N_; ++r) excl += v[((size_t)b * N_ + r) * C_ + t];
    }
    vd[t] = vsum[b * C_ + t] - excl;
    __syncthreads();
    if (t < CN_) {
        float s = 0.f;
        for (int c = 0; c < C_; ++c) s += vd[c] * Wv[c * CN_ + t];
        S[(b * M_ + m) * CN_ + t] = s;
    }
}

// ---------- a[r] = q[r,:]·wq1 ; kb[r] = k[r,:]·wk1 ----------
__global__ __launch_bounds__(256) void kAB(const float* __restrict__ q,
                                           const float* __restrict__ k,
                                           const float* __restrict__ wq1,
                                           const float* __restrict__ wk1,
                                           float* __restrict__ a_ws,
                                           float* __restrict__ kb_ws) {
    int lane = threadIdx.x & 63;
    int wv = threadIdx.x >> 6;
    int r0 = blockIdx.x * 64 + wv * 16;   // 512 blocks * 64 rows
    float2 wqv = ((const float2*)wq1)[lane];
    float2 wkv = ((const float2*)wk1)[lane];
    for (int i = 0; i < 16; ++i) {
        int r = r0 + i;
        float2 qv = ((const float2*)(q + (size_t)r * C_))[lane];
        float2 kv = ((const float2*)(k + (size_t)r * C_))[lane];
        float ta = qv.x * wqv.x + qv.y * wqv.y;
        float tk = kv.x * wkv.x + kv.y * wkv.y;
#pragma unroll
        for (int s = 1; s < 64; s <<= 1) {
            ta += __shfl_xor(ta, s);
            tk += __shfl_xor(tk, s);
        }
        if (lane == 0) { a_ws[r] = ta; kb_ws[r] = tk; }
    }
}

// ---------- big pass over pe: pdot[b,n,m] = pe·w_sa1 ; S += sum_n pe ----------
__global__ __launch_bounds__(256) void kPE(const float* __restrict__ pe,
                                           const float* __restrict__ w1,
                                           float* __restrict__ pdot,
                                           float* __restrict__ S) {
    int g = blockIdx.x;           // 1024 blocks: 256 per b, 32 n each
    int b = g >> 8;
    int n0 = (g & 255) * 32;
    int lane = threadIdx.x & 63;
    int wv = threadIdx.x >> 6;
    float w1l = w1[lane];

    float acc[M_];
#pragma unroll
    for (int m = 0; m < M_; ++m) acc[m] = 0.f;

    int nbase = n0 + wv * 8;      // 8 units per wave, same b for whole block
    for (int i = 0; i < 8; ++i) {
        size_t u = (size_t)b * N_ + (size_t)(nbase + i);
        const float* p = pe + u * (size_t)(M_ * CN_);
        float pd = 0.f;
#pragma unroll
        for (int m = 0; m < M_; ++m) {
            float x = p[m * CN_ + lane];
            acc[m] += x;
            float t = x * w1l;
#pragma unroll
            for (int s = 1; s < 64; s <<= 1) t += __shfl_xor(t, s);
            if (lane == m) pd = t;
        }
        if (lane < M_) pdot[u * M_ + lane] = pd;
    }

    __shared__ float lps[4][M_ * CN_];
#pragma unroll
    for (int m = 0; m < M_; ++m) lps[wv][m * CN_ + lane] = acc[m];
    __syncthreads();
    for (int i = 0; i < 8; ++i) {
        int idx = i * 256 + threadIdx.x;
        float s4 = lps[0][idx] + lps[1][idx] + lps[2][idx] + lps[3][idx];
        atomicAdd(&S[b * (M_ * CN_) + idx], s4);
    }
}

// ---------- finalize: softmax(logits) @ S @ w_sa2 ----------
__global__ __launch_bounds__(256) void kOut(const float* __restrict__ pdot,
                                            const float* __restrict__ a_ws,
                                            const float* __restrict__ kb_ws,
                                            const float* __restrict__ S,
                                            const float* __restrict__ w2,
                                            float* __restrict__ out) {
    int g = blockIdx.x;        // 512 blocks: 128 per b, 64 n each
    int b = g >> 7;
    int n0 = (g & 127) * 64;
    int t = threadIdx.x;
    int lane = t & 63, wv = t >> 6;

    __shared__ float w2l[CN_ * C_];   // 32 KB
    __shared__ float Sl[M_ * CN_];    // 8 KB
    for (int i = t; i < CN_ * C_; i += 256) w2l[i] = w2[i];
    for (int i = t; i < M_ * CN_; i += 256) Sl[i] = S[b * (M_ * CN_) + i];
    __syncthreads();

    const float* kbb = kb_ws + (size_t)b * N_;
    for (int i = 0; i < 16; ++i) {
        int n = n0 + wv * 16 + i;
        size_t u = (size_t)b * N_ + (size_t)n;

        float lg = -INFINITY;
        if (lane < M_) {
            float pd = pdot[u * M_ + lane];
            int j = n + lane - 16;
            float kbm = (j >= 0 && j < N_) ? kbb[j] : 0.f;
            lg = a_ws[u] + pd - kbm;
        }
        float mx = lg;
#pragma unroll
        for (int s = 1; s < 32; s <<= 1) mx = fmaxf(mx, __shfl_xor(mx, s));
        float e = (lane < M_) ? __expf(lg - mx) : 0.f;
        float sm = e;
#pragma unroll
        for (int s = 1; s < 32; s <<= 1) sm += __shfl_xor(sm, s);
        float sc = e / sm;            // valid in lanes < 32 only

        // p_attn[c=lane] = sum_m scores[m] * S[m][c]
        float pa = 0.f;
#pragma unroll
        for (int m = 0; m < M_; ++m) pa += __shfl(sc, m) * Sl[m * CN_ + lane];

        // out[cc=lane], out[cc=lane+64] = sum_c pa[c] * w2[c][cc]
        float o1 = 0.f, o2 = 0.f;
#pragma unroll
        for (int c = 0; c < CN_; ++c) {
            float p = __shfl(pa, c);
            o1 += p * w2l[c * C_ + lane];
            o2 += p * w2l[c * C_ + lane + 64];
        }
        float* orow = out + u * (size_t)C_;
        orow[lane] = o1;
        orow[lane + 64] = o2;
    }
}

extern "C" void kernel_launch(void* const* d_in, const int* in_sizes, int n_in,
                              void* d_out, int out_size, void* d_ws, size_t ws_size,
                              hipStream_t stream) {
    const float* q  = (const float*)d_in[0];
    const float* k  = (const float*)d_in[1];
    const float* v  = (const float*)d_in[2];
    const float* pe = (const float*)d_in[3];
    const float* Wq = (const float*)d_in[4];
    const float* Wk = (const float*)d_in[5];
    const float* Wv = (const float*)d_in[6];
    const float* w1 = (const float*)d_in[7];
    const float* w2 = (const float*)d_in[8];
    float* out = (float*)d_out;
    float* ws  = (float*)d_ws;

    // workspace layout (floats)
    float* S     = ws;                    // 4*32*64      = 8192
    float* vsum  = ws + 8192;             // 4*128        = 512
    float* wq1   = ws + 8704;             // 128
    float* wk1   = ws + 8832;             // 128
    float* a_ws  = ws + 8960;             // 4*8192       = 32768
    float* kb_ws = ws + 8960 + 32768;     // 32768
    float* pdot  = ws + 8960 + 65536;     // 4*8192*32    = 1048576
    // total ~4.3 MB

    hipMemsetAsync(vsum, 0, 512 * sizeof(float), stream);
    kW<<<1, 256, 0, stream>>>(Wq, Wk, w1, wq1, wk1);
    kVsum<<<256, 256, 0, stream>>>(v, vsum);
    kSinit<<<128, 128, 0, stream>>>(v, Wv, vsum, S);
    kAB<<<512, 256, 0, stream>>>(q, k, wq1, wk1, a_ws, kb_ws);
    kPE<<<1024, 256, 0, stream>>>(pe, w1, pdot, S);
    kOut<<<512, 256, 0, stream>>>(pdot, a_ws, kb_ws, S, w2, out);
}

// Round 2
// 166.201 us; speedup vs baseline: 1.1245x; 1.1245x over previous
//
#include <hip/hip_runtime.h>
#include <math.h>

#define B_ 4
#define N_ 8192
#define C_ 128
#define CN_ 64
#define M_ 32

// ================= K1: vsum partials (blocks 0..255) + a/kb rows (blocks 256..511) =================
__global__ __launch_bounds__(256) void k1(const float* __restrict__ q,
                                          const float* __restrict__ k,
                                          const float* __restrict__ v,
                                          const float* __restrict__ Wq,
                                          const float* __restrict__ Wk,
                                          const float* __restrict__ w1,
                                          float* __restrict__ vsum_part,
                                          float* __restrict__ a_ws,
                                          float* __restrict__ kb_ws) {
    int g = blockIdx.x;
    int t = threadIdx.x;
    if (g < 256) {
        // --- vsum partial: 64 chunks per b, 128 rows each, no atomics ---
        int b = g >> 6;
        int chunk = g & 63;
        const float* vb = v + ((size_t)b * N_ + (size_t)chunk * 128) * C_;
        int c4 = t & 31, h = t >> 5;           // 32 float4 per row; 8 rows in flight
        float4 acc = make_float4(0.f, 0.f, 0.f, 0.f);
        for (int r = h; r < 128; r += 8) {
            float4 x = ((const float4*)(vb + (size_t)r * C_))[c4];
            acc.x += x.x; acc.y += x.y; acc.z += x.z; acc.w += x.w;
        }
        __shared__ float4 red[256];
        red[t] = acc;
        __syncthreads();
        if (t < 32) {
            float4 s = red[t];
            for (int i = 1; i < 8; ++i) {
                float4 x = red[i * 32 + t];
                s.x += x.x; s.y += x.y; s.z += x.z; s.w += x.w;
            }
            ((float4*)(vsum_part + (size_t)g * C_))[t] = s;
        }
    } else {
        // --- a[r]=q[r,:]·(Wq@w1), kb[r]=k[r,:]·(Wk@w1); weights folded in-block ---
        int gg = g - 256;                       // 0..255, 128 rows each
        __shared__ float wq1l[C_], wk1l[C_];
        if (t < C_) {
            float s = 0.f;
            for (int c2 = 0; c2 < CN_; ++c2) s += Wq[t * CN_ + c2] * w1[c2];
            wq1l[t] = s;
        } else {
            int c = t - C_;
            float s = 0.f;
            for (int c2 = 0; c2 < CN_; ++c2) s += Wk[c * CN_ + c2] * w1[c2];
            wk1l[c] = s;
        }
        __syncthreads();
        int lane = t & 63, wv = t >> 6;
        int grp = lane >> 4, li = lane & 15;    // 16-lane groups: group handles one row
        float4 wq0 = ((const float4*)wq1l)[li * 2];
        float4 wq1v = ((const float4*)wq1l)[li * 2 + 1];
        float4 wk0 = ((const float4*)wk1l)[li * 2];
        float4 wk1v = ((const float4*)wk1l)[li * 2 + 1];
        int r0 = gg * 128 + wv * 32;
        for (int it = 0; it < 8; ++it) {
            int r = r0 + it * 4 + grp;
            const float4* qr = (const float4*)(q + (size_t)r * C_);
            const float4* kr = (const float4*)(k + (size_t)r * C_);
            float4 x0 = qr[li * 2], x1 = qr[li * 2 + 1];
            float ta = x0.x * wq0.x + x0.y * wq0.y + x0.z * wq0.z + x0.w * wq0.w
                     + x1.x * wq1v.x + x1.y * wq1v.y + x1.z * wq1v.z + x1.w * wq1v.w;
            float4 y0 = kr[li * 2], y1 = kr[li * 2 + 1];
            float tk = y0.x * wk0.x + y0.y * wk0.y + y0.z * wk0.z + y0.w * wk0.w
                     + y1.x * wk1v.x + y1.y * wk1v.y + y1.z * wk1v.z + y1.w * wk1v.w;
            ta += __shfl_xor(ta, 1); ta += __shfl_xor(ta, 2);
            ta += __shfl_xor(ta, 4); ta += __shfl_xor(ta, 8);
            tk += __shfl_xor(tk, 1); tk += __shfl_xor(tk, 2);
            tk += __shfl_xor(tk, 4); tk += __shfl_xor(tk, 8);
            if (li == 0) { a_ws[r] = ta; kb_ws[r] = tk; }
        }
    }
}

// ================= K2: S[b,m,:] = (vsum - edge_rows) @ Wv =================
__global__ __launch_bounds__(128) void k2(const float* __restrict__ v,
                                          const float* __restrict__ Wv,
                                          const float* __restrict__ vsum_part,
                                          float* __restrict__ S) {
    int g = blockIdx.x;   // 128 blocks = (b,m)
    int b = g >> 5, m = g & 31;
    int t = threadIdx.x;  // t = c
    __shared__ float vd[C_];
    float s = 0.f;
    const float* vp = vsum_part + (size_t)b * 64 * C_;
    for (int i = 0; i < 64; ++i) s += vp[i * C_ + t];
    float excl = 0.f;
    if (m > 16) {
        for (int r = 0; r < m - 16; ++r) excl += v[((size_t)b * N_ + r) * C_ + t];
    } else if (m < 16) {
        for (int r = N_ - (16 - m); r < N_; ++r) excl += v[((size_t)b * N_ + r) * C_ + t];
    }
    vd[t] = s - excl;
    __syncthreads();
    if (t < CN_) {
        float acc = 0.f;
        for (int c = 0; c < C_; ++c) acc += vd[c] * Wv[c * CN_ + t];
        S[(b * M_ + m) * CN_ + t] = acc;
    }
}

// ================= kPE: pdot[b,n,m]=pe·w1 ; S += sum_n pe (float4, 16-lane groups) =================
__global__ __launch_bounds__(256) void kPE(const float* __restrict__ pe,
                                           const float* __restrict__ w1,
                                           float* __restrict__ pdot,
                                           float* __restrict__ S) {
    int g = blockIdx.x;           // 1024 blocks: 256 per b, 32 n each
    int b = g >> 8;
    int n0 = (g & 255) * 32;
    int t = threadIdx.x;
    int lane = t & 63, wv = t >> 6;
    int grp = lane >> 4, li = lane & 15;
    float4 w1v = ((const float4*)w1)[li];   // c = li*4..+3

    float4 acc[8];                           // acc[j]: m=j*4+grp, c=li*4..+3
#pragma unroll
    for (int j = 0; j < 8; ++j) acc[j] = make_float4(0.f, 0.f, 0.f, 0.f);

    __shared__ float lpd[4][8][M_];          // per-wave pdot staging (4 KB)
    int nbase = n0 + wv * 8;
    for (int i = 0; i < 8; ++i) {
        size_t u = (size_t)b * N_ + (size_t)(nbase + i);
        const float4* p = (const float4*)(pe + u * (size_t)(M_ * CN_));
#pragma unroll
        for (int j = 0; j < 8; ++j) {
            float4 x = p[j * 64 + lane];     // chunk j: m = j*4..j*4+3
            acc[j].x += x.x; acc[j].y += x.y; acc[j].z += x.z; acc[j].w += x.w;
            float tv = x.x * w1v.x + x.y * w1v.y + x.z * w1v.z + x.w * w1v.w;
            tv += __shfl_xor(tv, 1); tv += __shfl_xor(tv, 2);
            tv += __shfl_xor(tv, 4); tv += __shfl_xor(tv, 8);
            if (li == 0) lpd[wv][i][j * 4 + grp] = tv;
        }
    }
    __syncthreads();
    // coalesced pdot write: each wave's 8 rows x 32 m = 256 contiguous floats
    {
        float* pout = pdot + ((size_t)b * N_ + (size_t)nbase) * M_;
        const float* lp = &lpd[wv][0][0];
#pragma unroll
        for (int i2 = 0; i2 < 4; ++i2) pout[i2 * 64 + lane] = lp[i2 * 64 + lane];
    }
    // S accumulation: acc[j] sits at float4 index (j*4+grp)*16+li = j*64+lane
    __shared__ float4 lps4[4][512];          // 32 KB
#pragma unroll
    for (int j = 0; j < 8; ++j) lps4[wv][j * 64 + lane] = acc[j];
    __syncthreads();
#pragma unroll
    for (int i2 = 0; i2 < 2; ++i2) {
        int idx = i2 * 256 + t;
        float4 s0 = lps4[0][idx], s1 = lps4[1][idx], s2 = lps4[2][idx], s3 = lps4[3][idx];
        float4 sm;
        sm.x = s0.x + s1.x + s2.x + s3.x;
        sm.y = s0.y + s1.y + s2.y + s3.y;
        sm.z = s0.z + s1.z + s2.z + s3.z;
        sm.w = s0.w + s1.w + s2.w + s3.w;
        float* dst = S + (size_t)b * (M_ * CN_) + (size_t)idx * 4;
        atomicAdd(dst + 0, sm.x); atomicAdd(dst + 1, sm.y);
        atomicAdd(dst + 2, sm.z); atomicAdd(dst + 3, sm.w);
    }
}

// ================= kOut: softmax(logits) @ S @ w_sa2 =================
__global__ __launch_bounds__(256) void kOut(const float* __restrict__ pdot,
                                            const float* __restrict__ a_ws,
                                            const float* __restrict__ kb_ws,
                                            const float* __restrict__ S,
                                            const float* __restrict__ w2,
                                            float* __restrict__ out) {
    int g = blockIdx.x;        // 512 blocks: 128 per b, 64 n each
    int b = g >> 7;
    int n0 = (g & 127) * 64;
    int t = threadIdx.x;
    int lane = t & 63, wv = t >> 6;

    __shared__ float w2l[CN_ * C_];   // 32 KB
    __shared__ float Sl[M_ * CN_];    // 8 KB
    for (int i = t; i < CN_ * C_; i += 256) w2l[i] = w2[i];
    for (int i = t; i < M_ * CN_; i += 256) Sl[i] = S[b * (M_ * CN_) + i];
    __syncthreads();

    const float* kbb = kb_ws + (size_t)b * N_;
    for (int i = 0; i < 16; ++i) {
        int n = n0 + wv * 16 + i;
        size_t u = (size_t)b * N_ + (size_t)n;

        float lg = -INFINITY;
        if (lane < M_) {
            float pd = pdot[u * M_ + lane];
            int j = n + lane - 16;
            float kbm = (j >= 0 && j < N_) ? kbb[j] : 0.f;
            lg = a_ws[u] + pd - kbm;
        }
        float mx = lg;
#pragma unroll
        for (int s = 1; s < 32; s <<= 1) mx = fmaxf(mx, __shfl_xor(mx, s));
        float e = (lane < M_) ? __expf(lg - mx) : 0.f;
        float sm = e;
#pragma unroll
        for (int s = 1; s < 32; s <<= 1) sm += __shfl_xor(sm, s);
        float sc = e / sm;            // valid in lanes < 32

        float pa = 0.f;
#pragma unroll
        for (int m = 0; m < M_; ++m) pa += __shfl(sc, m) * Sl[m * CN_ + lane];

        float o1 = 0.f, o2 = 0.f;
#pragma unroll
        for (int c = 0; c < CN_; ++c) {
            float p = __shfl(pa, c);
            o1 += p * w2l[c * C_ + lane];
            o2 += p * w2l[c * C_ + lane + 64];
        }
        float* orow = out + u * (size_t)C_;
        orow[lane] = o1;
        orow[lane + 64] = o2;
    }
}

extern "C" void kernel_launch(void* const* d_in, const int* in_sizes, int n_in,
                              void* d_out, int out_size, void* d_ws, size_t ws_size,
                              hipStream_t stream) {
    const float* q  = (const float*)d_in[0];
    const float* k  = (const float*)d_in[1];
    const float* v  = (const float*)d_in[2];
    const float* pe = (const float*)d_in[3];
    const float* Wq = (const float*)d_in[4];
    const float* Wk = (const float*)d_in[5];
    const float* Wv = (const float*)d_in[6];
    const float* w1 = (const float*)d_in[7];
    const float* w2 = (const float*)d_in[8];
    float* out = (float*)d_out;
    float* ws  = (float*)d_ws;

    // workspace layout (floats)
    float* S         = ws;                      // 4*32*64   = 8192
    float* vsum_part = ws + 8192;               // 256*128   = 32768
    float* a_ws      = ws + 8192 + 32768;       // 32768
    float* kb_ws     = a_ws + 32768;            // 32768
    float* pdot      = kb_ws + 32768;           // 4*8192*32 = 1048576

    k1<<<512, 256, 0, stream>>>(q, k, v, Wq, Wk, w1, vsum_part, a_ws, kb_ws);
    k2<<<128, 128, 0, stream>>>(v, Wv, vsum_part, S);
    kPE<<<1024, 256, 0, stream>>>(pe, w1, pdot, S);
    kOut<<<512, 256, 0, stream>>>(pdot, a_ws, kb_ws, S, w2, out);
}

// Round 3
// 120.413 us; speedup vs baseline: 1.5520x; 1.3803x over previous
//
#include <hip/hip_runtime.h>
#include <math.h>

#define B_ 4
#define N_ 8192
#define C_ 128
#define CN_ 64
#define M_ 32

#define ROR1 0x121
#define ROR2 0x122
#define ROR4 0x124
#define ROR8 0x128

template<int CTRL>
__device__ __forceinline__ float dpp_add(float x) {
    int y = __builtin_amdgcn_update_dpp(0, __float_as_int(x), CTRL, 0xF, 0xF, true);
    return x + __int_as_float(y);
}
template<int CTRL>
__device__ __forceinline__ float dpp_max(float x) {
    int y = __builtin_amdgcn_update_dpp(0, __float_as_int(x), CTRL, 0xF, 0xF, true);
    return fmaxf(x, __int_as_float(y));
}
__device__ __forceinline__ float red16_add(float x) {
    return dpp_add<ROR1>(dpp_add<ROR2>(dpp_add<ROR4>(dpp_add<ROR8>(x))));
}

// ================= K1: vsum partials (blocks 0..255) + a/kb rows (blocks 256..511) =================
__global__ __launch_bounds__(256) void k1(const float* __restrict__ q,
                                          const float* __restrict__ k,
                                          const float* __restrict__ v,
                                          const float* __restrict__ Wq,
                                          const float* __restrict__ Wk,
                                          const float* __restrict__ w1,
                                          float* __restrict__ vsum_part,
                                          float* __restrict__ a_ws,
                                          float* __restrict__ kb_ws) {
    int g = blockIdx.x;
    int t = threadIdx.x;
    if (g < 256) {
        int b = g >> 6;
        int chunk = g & 63;
        const float* vb = v + ((size_t)b * N_ + (size_t)chunk * 128) * C_;
        int c4 = t & 31, h = t >> 5;
        float4 acc = make_float4(0.f, 0.f, 0.f, 0.f);
        for (int r = h; r < 128; r += 8) {
            float4 x = ((const float4*)(vb + (size_t)r * C_))[c4];
            acc.x += x.x; acc.y += x.y; acc.z += x.z; acc.w += x.w;
        }
        __shared__ float4 red[256];
        red[t] = acc;
        __syncthreads();
        if (t < 32) {
            float4 s = red[t];
            for (int i = 1; i < 8; ++i) {
                float4 x = red[i * 32 + t];
                s.x += x.x; s.y += x.y; s.z += x.z; s.w += x.w;
            }
            ((float4*)(vsum_part + (size_t)g * C_))[t] = s;
        }
    } else {
        int gg = g - 256;
        __shared__ float wq1l[C_], wk1l[C_];
        if (t < C_) {
            float s = 0.f;
            for (int c2 = 0; c2 < CN_; ++c2) s += Wq[t * CN_ + c2] * w1[c2];
            wq1l[t] = s;
        } else {
            int c = t - C_;
            float s = 0.f;
            for (int c2 = 0; c2 < CN_; ++c2) s += Wk[c * CN_ + c2] * w1[c2];
            wk1l[c] = s;
        }
        __syncthreads();
        int lane = t & 63, wv = t >> 6;
        int grp = lane >> 4, li = lane & 15;
        float4 wq0 = ((const float4*)wq1l)[li * 2];
        float4 wq1v = ((const float4*)wq1l)[li * 2 + 1];
        float4 wk0 = ((const float4*)wk1l)[li * 2];
        float4 wk1v = ((const float4*)wk1l)[li * 2 + 1];
        int r0 = gg * 128 + wv * 32;
        for (int it = 0; it < 8; ++it) {
            int r = r0 + it * 4 + grp;
            const float4* qr = (const float4*)(q + (size_t)r * C_);
            const float4* kr = (const float4*)(k + (size_t)r * C_);
            float4 x0 = qr[li * 2], x1 = qr[li * 2 + 1];
            float ta = x0.x * wq0.x + x0.y * wq0.y + x0.z * wq0.z + x0.w * wq0.w
                     + x1.x * wq1v.x + x1.y * wq1v.y + x1.z * wq1v.z + x1.w * wq1v.w;
            float4 y0 = kr[li * 2], y1 = kr[li * 2 + 1];
            float tk = y0.x * wk0.x + y0.y * wk0.y + y0.z * wk0.z + y0.w * wk0.w
                     + y1.x * wk1v.x + y1.y * wk1v.y + y1.z * wk1v.z + y1.w * wk1v.w;
            ta = red16_add(ta);
            tk = red16_add(tk);
            if (li == 0) { a_ws[r] = ta; kb_ws[r] = tk; }
        }
    }
}

// ================= K2: Sinit[b,m,:] = (vsum - edge_rows) @ Wv =================
__global__ __launch_bounds__(128) void k2(const float* __restrict__ v,
                                          const float* __restrict__ Wv,
                                          const float* __restrict__ vsum_part,
                                          float* __restrict__ Sinit) {
    int g = blockIdx.x;   // 128 blocks = (b,m)
    int b = g >> 5, m = g & 31;
    int t = threadIdx.x;  // t = c (0..127)
    __shared__ float vd[C_];
    float s = 0.f;
    const float* vp = vsum_part + (size_t)b * 64 * C_;
    for (int i = 0; i < 64; ++i) s += vp[i * C_ + t];
    float excl = 0.f;
    if (m > 16) {
        for (int r = 0; r < m - 16; ++r) excl += v[((size_t)b * N_ + r) * C_ + t];
    } else if (m < 16) {
        for (int r = N_ - (16 - m); r < N_; ++r) excl += v[((size_t)b * N_ + r) * C_ + t];
    }
    vd[t] = s - excl;
    __syncthreads();
    if (t < CN_) {
        float acc = 0.f;
        for (int c = 0; c < C_; ++c) acc += vd[c] * Wv[c * CN_ + t];
        Sinit[(b * M_ + m) * CN_ + t] = acc;
    }
}

// ================= kPE: pdot = pe·w1 ; per-block partials of sum_n pe (no atomics) =================
__global__ __launch_bounds__(256) void kPE(const float* __restrict__ pe,
                                           const float* __restrict__ w1,
                                           float* __restrict__ pdot,
                                           float* __restrict__ pe_part) {
    int g = blockIdx.x;           // 1024 blocks: 256 per b, 32 n each
    int b = g >> 8;
    int n0 = (g & 255) * 32;
    int t = threadIdx.x;
    int lane = t & 63, wv = t >> 6;
    int grp = lane >> 4, li = lane & 15;
    float4 w1v = ((const float4*)w1)[li];

    float4 acc[8];
#pragma unroll
    for (int j = 0; j < 8; ++j) acc[j] = make_float4(0.f, 0.f, 0.f, 0.f);

    __shared__ float lpd[4][8][M_];
    int nbase = n0 + wv * 8;
    for (int i = 0; i < 8; ++i) {
        size_t u = (size_t)b * N_ + (size_t)(nbase + i);
        const float4* p = (const float4*)(pe + u * (size_t)(M_ * CN_));
#pragma unroll
        for (int j = 0; j < 8; ++j) {
            float4 x = p[j * 64 + lane];
            acc[j].x += x.x; acc[j].y += x.y; acc[j].z += x.z; acc[j].w += x.w;
            float tv = x.x * w1v.x + x.y * w1v.y + x.z * w1v.z + x.w * w1v.w;
            tv = red16_add(tv);
            if (li == 0) lpd[wv][i][j * 4 + grp] = tv;
        }
    }
    // per-wave pdot write (wave-local LDS, compiler inserts lgkmcnt)
    {
        float* pout = pdot + ((size_t)b * N_ + (size_t)nbase) * M_;
        const float* lp = &lpd[wv][0][0];
#pragma unroll
        for (int i2 = 0; i2 < 4; ++i2) pout[i2 * 64 + lane] = lp[i2 * 64 + lane];
    }
    // block-level partial: reduce 4 waves in LDS, write to pe_part[g]
    __shared__ float4 lps4[4][512];
#pragma unroll
    for (int j = 0; j < 8; ++j) lps4[wv][j * 64 + lane] = acc[j];
    __syncthreads();
    float4* pp = (float4*)(pe_part + (size_t)g * (M_ * CN_));
#pragma unroll
    for (int i2 = 0; i2 < 2; ++i2) {
        int idx = i2 * 256 + t;
        float4 s0 = lps4[0][idx], s1 = lps4[1][idx], s2 = lps4[2][idx], s3 = lps4[3][idx];
        float4 sm;
        sm.x = s0.x + s1.x + s2.x + s3.x;
        sm.y = s0.y + s1.y + s2.y + s3.y;
        sm.z = s0.z + s1.z + s2.z + s3.z;
        sm.w = s0.w + s1.w + s2.w + s3.w;
        pp[idx] = sm;
    }
}

// ================= kS: S = Sinit + sum_partials ; SW2 = S @ w_sa2 =================
__global__ __launch_bounds__(256) void kS(const float* __restrict__ pe_part,
                                          const float* __restrict__ Sinit,
                                          const float* __restrict__ w2,
                                          float* __restrict__ SW2) {
    int b = blockIdx.x >> 3, seg = blockIdx.x & 7;   // 32 blocks
    int t = threadIdx.x;
    int off = seg * 256 + t;                          // float index in [0,2048)
    float acc = Sinit[b * (M_ * CN_) + off];
    const float* pp = pe_part + (size_t)b * 256 * (M_ * CN_) + off;
    float a0 = 0.f, a1 = 0.f, a2 = 0.f, a3 = 0.f;
#pragma unroll 4
    for (int p = 0; p < 256; p += 4) {
        a0 += pp[(size_t)(p + 0) * (M_ * CN_)];
        a1 += pp[(size_t)(p + 1) * (M_ * CN_)];
        a2 += pp[(size_t)(p + 2) * (M_ * CN_)];
        a3 += pp[(size_t)(p + 3) * (M_ * CN_)];
    }
    acc += (a0 + a1) + (a2 + a3);
    __shared__ float Sl[4][CN_];
    Sl[t >> 6][t & 63] = acc;      // off = m*64 + c -> m_local = t>>6, c = t&63
    __syncthreads();
    int cc = t & 127;
#pragma unroll
    for (int pass = 0; pass < 2; ++pass) {
        int ml = (t >> 7) + pass * 2;
        float s = 0.f;
#pragma unroll
        for (int c = 0; c < CN_; ++c) s += Sl[ml][c] * w2[c * C_ + cc];
        SW2[((size_t)b * M_ + seg * 4 + ml) * C_ + cc] = s;
    }
}

// ================= kOut: softmax(logits) -> LDS ; out = scores @ SW2 (SW2 in regs) =================
__global__ __launch_bounds__(256) void kOut(const float* __restrict__ pdot,
                                            const float* __restrict__ a_ws,
                                            const float* __restrict__ kb_ws,
                                            const float* __restrict__ SW2,
                                            float* __restrict__ out) {
    int g = blockIdx.x;        // 512 blocks: 128 per b, 64 rows each
    int b = g >> 7;
    int n0 = (g & 127) * 64;
    int t = threadIdx.x;
    int lane = t & 63, wv = t >> 6;
    __shared__ float scl[64][M_];    // 8 KB

    // Phase A: half-wave per row, DPP softmax
    {
        int hw = t >> 5, m = t & 31;
        const float* kbb = kb_ws + (size_t)b * N_;
        for (int i = 0; i < 8; ++i) {
            int r = hw * 8 + i;
            int n = n0 + r;
            size_t u = (size_t)b * N_ + (size_t)n;
            float pd = pdot[u * M_ + m];
            int j = n + m - 16;
            float kbm = (j >= 0 && j < N_) ? kbb[j] : 0.f;
            float lg = a_ws[u] + pd - kbm;
            float mx = dpp_max<ROR1>(dpp_max<ROR2>(dpp_max<ROR4>(dpp_max<ROR8>(lg))));
            mx = fmaxf(mx, __shfl_xor(mx, 16));
            float e = __expf(lg - mx);
            float sm = red16_add(e);
            sm += __shfl_xor(sm, 16);
            scl[r][m] = e / sm;
        }
    }
    // SW2 -> registers (cc = 2*lane, 2*lane+1)
    float2 sw2[M_];
    {
        const float2* sw2g = (const float2*)(SW2 + (size_t)b * M_ * C_);
#pragma unroll
        for (int mm = 0; mm < M_; ++mm) sw2[mm] = sw2g[mm * 64 + lane];
    }
    __syncthreads();
    // Phase B: wave per row, uniform b128 score reads, FMA in regs
    for (int i = 0; i < 16; ++i) {
        int r = wv * 16 + i;
        const float4* sp = (const float4*)(&scl[r][0]);
        float ox = 0.f, oy = 0.f;
#pragma unroll
        for (int j4 = 0; j4 < 8; ++j4) {
            float4 s4 = sp[j4];
            ox += s4.x * sw2[j4 * 4 + 0].x; oy += s4.x * sw2[j4 * 4 + 0].y;
            ox += s4.y * sw2[j4 * 4 + 1].x; oy += s4.y * sw2[j4 * 4 + 1].y;
            ox += s4.z * sw2[j4 * 4 + 2].x; oy += s4.z * sw2[j4 * 4 + 2].y;
            ox += s4.w * sw2[j4 * 4 + 3].x; oy += s4.w * sw2[j4 * 4 + 3].y;
        }
        size_t u = (size_t)b * N_ + (size_t)(n0 + r);
        float2 o; o.x = ox; o.y = oy;
        ((float2*)(out + u * C_))[lane] = o;
    }
}

extern "C" void kernel_launch(void* const* d_in, const int* in_sizes, int n_in,
                              void* d_out, int out_size, void* d_ws, size_t ws_size,
                              hipStream_t stream) {
    const float* q  = (const float*)d_in[0];
    const float* k  = (const float*)d_in[1];
    const float* v  = (const float*)d_in[2];
    const float* pe = (const float*)d_in[3];
    const float* Wq = (const float*)d_in[4];
    const float* Wk = (const float*)d_in[5];
    const float* Wv = (const float*)d_in[6];
    const float* w1 = (const float*)d_in[7];
    const float* w2 = (const float*)d_in[8];
    float* out = (float*)d_out;
    float* ws  = (float*)d_ws;

    // workspace layout (floats)
    float* Sinit     = ws;                          // 4*2048    = 8192
    float* vsum_part = Sinit + 8192;                // 256*128   = 32768
    float* a_ws      = vsum_part + 32768;           // 32768
    float* kb_ws     = a_ws + 32768;                // 32768
    float* pdot      = kb_ws + 32768;               // 4*8192*32 = 1048576
    float* pe_part   = pdot + 1048576;              // 1024*2048 = 2097152
    float* SW2       = pe_part + 2097152;           // 4*32*128  = 16384
    // total ~13.1 MB

    k1 <<<512, 256, 0, stream>>>(q, k, v, Wq, Wk, w1, vsum_part, a_ws, kb_ws);
    k2 <<<128, 128, 0, stream>>>(v, Wv, vsum_part, Sinit);
    kPE<<<1024, 256, 0, stream>>>(pe, w1, pdot, pe_part);
    kS <<<32, 256, 0, stream>>>(pe_part, Sinit, w2, SW2);
    kOut<<<512, 256, 0, stream>>>(pdot, a_ws, kb_ws, SW2, out);
}